// Round 16
// baseline (233.015 us; speedup 1.0000x reference)
//
#include <hip/hip_runtime.h>
#include <hip/hip_bf16.h>

#define BATCH  128
#define WIDTH  8192
#define DIM    64
#define FILT   32
#define KSZ    3
#define WOUT   8190
#define RPW    14     // valid output rows per wave per step (rows 14,15 masked)
#define RST    16     // rows staged per wave per step (private region)
#define NW     8      // waves per block (512 threads)
#define WT     112    // NW*RPW output rows per block-step
#define TPB    19     // steps per block
#define NBX    4      // 4*19*112 = 8512 >= 8190; 512 blocks = 2/CU, all resident
#define XR     (NW*RST + 2)   // 130 rows per buffer (2 pad rows: garbage, masked)

typedef __attribute__((ext_vector_type(8))) _Float16 f16x8;
typedef __attribute__((ext_vector_type(4))) float f32x4;
typedef __attribute__((ext_vector_type(4))) unsigned u32x4;

__global__ void zero_cnt(unsigned* cnt) {
  cnt[threadIdx.x] = 0u;   // 128 per-batch arrival counters, reset every call
}

// Fused, NO intermediate, NO register-hold. Phase 1: r10-proven conv core,
// store UNNORMALIZED f32 to out (128-B contiguous per (it,r)), block min/max
// -> mm. Per-batch soft barrier (4 blocks, r14-proven). Phase 2: in-place
// normalize of out (each thread re-reads exactly what it wrote).
__global__ __launch_bounds__(512, 4)
void conv_norm(const float* __restrict__ x, const float* __restrict__ ker,
               float* __restrict__ out, float* __restrict__ mm,
               unsigned* __restrict__ cnt)
{
  // Per-wave private double-buffered x rows: fp32; content swizzled:
  // xs[..][row][slot16] = x[row][slot16 ^ (row&7)]. Rows 128,129: never
  // staged; read only by masked outputs.
  __shared__ __align__(16) float xs[2][XR * DIM];      // 66,560 B
  __shared__ __align__(16) short ks[KSZ * FILT * DIM]; // 12,288 B
  __shared__ float red[2 * NW];

  const int t  = threadIdx.x;
  const int l  = t & 63;
  const int wv = t >> 6;
  const int b  = blockIdx.x >> 2;
  const int bx = blockIdx.x & 3;
  const int step0 = bx * TPB;
  const float* xb = x + (long)b * WIDTH * DIM;

  // Per-wave stage: 4 direct-to-LDS DMAs (1 KB = 4 rows) into OWN region.
  auto stage = [&](int bb, int step) {
    long gw0 = (long)(step0 + step) * WT + wv * RPW;
    char* lb = (char*)&xs[bb][0] + wv * (RST * DIM * 4);
    #pragma unroll
    for (int j = 0; j < 4; ++j) {
      int row_l = j * 4 + (l >> 4);
      int slot  = (l & 15) ^ (row_l & 7);
      long gr = gw0 + row_l;
      if (gr > WIDTH - 1) gr = WIDTH - 1;   // tail OOB guard (dup reads, L2-hot)
      __builtin_amdgcn_global_load_lds(
          (const __attribute__((address_space(1))) void*)(xb + gr * DIM + slot * 4),
          (__attribute__((address_space(3))) void*)(lb + j * 1024), 16, 0, 0);
    }
  };

  stage(0, 0);   // prologue prefetch; hides under weight staging

  // weights: fp32 [k][d][f] coalesced -> f16 LDS [k][f][d], XOR-swizzled (f&7)
  #pragma unroll
  for (int i = 0; i < 12; ++i) {
    int idx = t + i * 512;
    int k = idx >> 11, rem = idx & 2047;
    int d = rem >> 5,  f = rem & 31;
    _Float16 hv = (_Float16)ker[idx];
    int byte = ((k * FILT + f) * DIM + d) * 2;
    byte ^= (f & 7) << 4;
    ks[byte >> 1] = __builtin_bit_cast(short, hv);
  }
  __syncthreads();

  // Persistent B fragments (r10-proven): nt=0 -> filter 2*(l&15), nt=1 -> +1
  f16x8 Bf[KSZ][2][2];
  #pragma unroll
  for (int s = 0; s < KSZ; ++s)
    #pragma unroll
    for (int kh = 0; kh < 2; ++kh)
      #pragma unroll
      for (int nt = 0; nt < 2; ++nt) {
        int f  = 2 * (l & 15) + nt;
        int d0 = kh * 32 + (l >> 4) * 8;
        int byte = ((s * FILT + f) * DIM + d0) * 2;
        byte ^= (f & 7) << 4;
        Bf[s][kh][nt] = *reinterpret_cast<const f16x8*>(&ks[byte >> 1]);
      }

  float mx = -INFINITY, mn = INFINITY;
  int cur = 0;

  for (int it = 0; it < TPB; ++it) {
    // Counted vmcnt (r10-proven): newest 8 = S(it-1)[4] + L(it+1)[4]; in-order
    // retirement guarantees L(it) complete without waiting on fresh stores.
    if (it + 1 < TPB) {
      stage(cur ^ 1, it + 1);
      asm volatile("s_waitcnt vmcnt(8)" ::: "memory");
    } else {
      asm volatile("s_waitcnt vmcnt(4)" ::: "memory");   // newest 4 = S(T-2)
    }
    __builtin_amdgcn_sched_barrier(0);   // rule #18: pin ds_reads after the wait

    const float* xl = &xs[cur][0];
    f32x4 acc0 = (f32x4){0.f, 0.f, 0.f, 0.f};
    f32x4 acc1 = (f32x4){0.f, 0.f, 0.f, 0.f};

    #pragma unroll
    for (int s = 0; s < KSZ; ++s) {
      #pragma unroll
      for (int kh = 0; kh < 2; ++kh) {
        int ra = wv * RST + (l & 15) + s;   // rows 16,17 bleed: masked C-rows only
        int sg = kh * 8 + (l >> 4) * 2;
        int rb = ra & 7;
        f32x4 u0 = *reinterpret_cast<const f32x4*>(&xl[ra * DIM + ((sg    ) ^ rb) * 4]);
        f32x4 u1 = *reinterpret_cast<const f32x4*>(&xl[ra * DIM + ((sg + 1) ^ rb) * 4]);
        u32x4 pk;
        pk.x = __builtin_bit_cast(unsigned, __builtin_amdgcn_cvt_pkrtz(u0.x, u0.y));
        pk.y = __builtin_bit_cast(unsigned, __builtin_amdgcn_cvt_pkrtz(u0.z, u0.w));
        pk.z = __builtin_bit_cast(unsigned, __builtin_amdgcn_cvt_pkrtz(u1.x, u1.y));
        pk.w = __builtin_bit_cast(unsigned, __builtin_amdgcn_cvt_pkrtz(u1.z, u1.w));
        f16x8 av = __builtin_bit_cast(f16x8, pk);
        acc0 = __builtin_amdgcn_mfma_f32_16x16x32_f16(av, Bf[s][kh][0], acc0, 0, 0, 0);
        acc1 = __builtin_amdgcn_mfma_f32_16x16x32_f16(av, Bf[s][kh][1], acc1, 0, 0, 0);
      }
    }

    long gw0 = (long)(step0 + it) * WT + wv * RPW;
    #pragma unroll
    for (int r = 0; r < 4; ++r) {
      int wl = (l >> 4) * 4 + r;           // C-row = (lane>>4)*4+reg
      long gr = gw0 + wl;
      if (wl < RPW && gr < WOUT) {
        float v0 = acc0[r], v1 = acc1[r];  // filters 2*(l&15), 2*(l&15)+1
        mx = fmaxf(mx, fmaxf(v0, v1));
        mn = fminf(mn, fminf(v0, v1));
        float2 o; o.x = v0; o.y = v1;      // UNNORMALIZED; fixed up in phase 2
        *reinterpret_cast<float2*>(out + ((long)b * WOUT + gr) * FILT + 2 * (l & 15)) = o;
      }
    }
    cur ^= 1;
  }

  // ---- block min/max -> mm, then per-batch soft barrier (r14-proven)
  #pragma unroll
  for (int off = 32; off > 0; off >>= 1) {
    mx = fmaxf(mx, __shfl_down(mx, off));
    mn = fminf(mn, __shfl_down(mn, off));
  }
  if (l == 0) { red[wv * 2] = mx; red[wv * 2 + 1] = mn; }
  __syncthreads();
  if (t == 0) {
    float Mx = -INFINITY, Mn = INFINITY;
    #pragma unroll
    for (int w = 0; w < NW; ++w) {
      Mx = fmaxf(Mx, red[w * 2]);
      Mn = fminf(Mn, red[w * 2 + 1]);
    }
    __hip_atomic_store(&mm[(b * NBX + bx) * 2],     Mx,
                       __ATOMIC_RELEASE, __HIP_MEMORY_SCOPE_AGENT);
    __hip_atomic_store(&mm[(b * NBX + bx) * 2 + 1], Mn,
                       __ATOMIC_RELEASE, __HIP_MEMORY_SCOPE_AGENT);
    __hip_atomic_fetch_add(&cnt[b], 1u, __ATOMIC_ACQ_REL, __HIP_MEMORY_SCOPE_AGENT);
    while (__hip_atomic_load(&cnt[b], __ATOMIC_ACQUIRE, __HIP_MEMORY_SCOPE_AGENT) < 4u)
      __builtin_amdgcn_s_sleep(2);
    float GMx = -INFINITY, GMn = INFINITY;
    #pragma unroll
    for (int i = 0; i < NBX; ++i) {
      GMx = fmaxf(GMx, __hip_atomic_load(&mm[(b * NBX + i) * 2],
                                         __ATOMIC_ACQUIRE, __HIP_MEMORY_SCOPE_AGENT));
      GMn = fminf(GMn, __hip_atomic_load(&mm[(b * NBX + i) * 2 + 1],
                                         __ATOMIC_ACQUIRE, __HIP_MEMORY_SCOPE_AGENT));
    }
    red[0] = GMx; red[1] = GMn;
  }
  __syncthreads();

  // ---- phase 2: in-place normalize of own rows (re-read own stores; drain
  // them first so the read-after-write is safe through L2)
  asm volatile("s_waitcnt vmcnt(0)" ::: "memory");
  const float Mn = red[1];
  const float rs = 1.0f / (red[0] - Mn);

  for (int it = 0; it < TPB; ++it) {
    long gw0 = (long)(step0 + it) * WT + wv * RPW;
    #pragma unroll
    for (int r = 0; r < 4; ++r) {
      int wl = (l >> 4) * 4 + r;
      long gr = gw0 + wl;
      if (wl < RPW && gr < WOUT) {
        float2* p = reinterpret_cast<float2*>(out + ((long)b * WOUT + gr) * FILT + 2 * (l & 15));
        float2 v = *p;
        v.x = (v.x - Mn) * rs;
        v.y = (v.y - Mn) * rs;
        *p = v;
      }
    }
  }
}

extern "C" void kernel_launch(void* const* d_in, const int* in_sizes, int n_in,
                              void* d_out, int out_size, void* d_ws, size_t ws_size,
                              hipStream_t stream) {
  const float* x   = (const float*)d_in[0];
  const float* ker = (const float*)d_in[1];
  float* out = (float*)d_out;
  float*    mm  = (float*)d_ws;                      // 1024 floats (4 KB)
  unsigned* cnt = (unsigned*)((char*)d_ws + 4096);   // 128 arrival counters

  zero_cnt<<<dim3(1), dim3(128), 0, stream>>>(cnt);
  conv_norm<<<dim3(NBX * BATCH), dim3(512), 0, stream>>>(x, ker, out, mm, cnt);
}

// Round 17
// 207.647 us; speedup vs baseline: 1.1222x; 1.1222x over previous
//
#include <hip/hip_runtime.h>
#include <hip/hip_bf16.h>

#define BATCH  128
#define WIDTH  8192
#define DIM    64
#define FILT   32
#define KSZ    3
#define WOUT   8190
#define RPW    14     // valid output rows per wave per step (rows 14,15 masked)
#define RST    16     // rows staged per wave per step (private region)
#define NW     8      // waves per block (512 threads)
#define WT     112    // NW*RPW output rows per block-step
#define TPB    19     // steps per block
#define NBX    4      // 4*19*112 = 8512 >= 8190; 512 blocks = 2/CU, all resident
#define XR     (NW*RST + 2)   // 130 rows per buffer (2 pad rows: garbage, masked)

typedef __attribute__((ext_vector_type(8))) _Float16 f16x8;
typedef __attribute__((ext_vector_type(4))) float f32x4;
typedef __attribute__((ext_vector_type(4))) unsigned u32x4;

__global__ void zero_cnt(unsigned* cnt) {
  cnt[threadIdx.x] = 0u;   // 128 per-batch arrival counters, reset every call
}

// Fused, no intermediate. Phase 1: r10-proven conv core, store UNNORMALIZED
// f32 to out, block min/max -> mm. Per-batch soft barrier with RELAXED polling
// (agent-acquire per poll = whole-L2 buffer_inv storm — the r14-r16 1.73 TB/s
// cap; one acquire FENCE after exit instead). Phase 2: in-place normalize.
__global__ __launch_bounds__(512, 4)
void conv_norm(const float* __restrict__ x, const float* __restrict__ ker,
               float* __restrict__ out, float* __restrict__ mm,
               unsigned* __restrict__ cnt)
{
  // Per-wave private double-buffered x rows: fp32; content swizzled:
  // xs[..][row][slot16] = x[row][slot16 ^ (row&7)]. Rows 128,129: never
  // staged; read only by masked outputs.
  __shared__ __align__(16) float xs[2][XR * DIM];      // 66,560 B
  __shared__ __align__(16) short ks[KSZ * FILT * DIM]; // 12,288 B
  __shared__ float red[2 * NW];

  const int t  = threadIdx.x;
  const int l  = t & 63;
  const int wv = t >> 6;
  const int b  = blockIdx.x >> 2;
  const int bx = blockIdx.x & 3;
  const int step0 = bx * TPB;
  const float* xb = x + (long)b * WIDTH * DIM;

  // Per-wave stage: 4 direct-to-LDS DMAs (1 KB = 4 rows) into OWN region.
  auto stage = [&](int bb, int step) {
    long gw0 = (long)(step0 + step) * WT + wv * RPW;
    char* lb = (char*)&xs[bb][0] + wv * (RST * DIM * 4);
    #pragma unroll
    for (int j = 0; j < 4; ++j) {
      int row_l = j * 4 + (l >> 4);
      int slot  = (l & 15) ^ (row_l & 7);
      long gr = gw0 + row_l;
      if (gr > WIDTH - 1) gr = WIDTH - 1;   // tail OOB guard (dup reads, L2-hot)
      __builtin_amdgcn_global_load_lds(
          (const __attribute__((address_space(1))) void*)(xb + gr * DIM + slot * 4),
          (__attribute__((address_space(3))) void*)(lb + j * 1024), 16, 0, 0);
    }
  };

  stage(0, 0);   // prologue prefetch; hides under weight staging

  // weights: fp32 [k][d][f] coalesced -> f16 LDS [k][f][d], XOR-swizzled (f&7)
  #pragma unroll
  for (int i = 0; i < 12; ++i) {
    int idx = t + i * 512;
    int k = idx >> 11, rem = idx & 2047;
    int d = rem >> 5,  f = rem & 31;
    _Float16 hv = (_Float16)ker[idx];
    int byte = ((k * FILT + f) * DIM + d) * 2;
    byte ^= (f & 7) << 4;
    ks[byte >> 1] = __builtin_bit_cast(short, hv);
  }
  __syncthreads();

  // Persistent B fragments (r10-proven): nt=0 -> filter 2*(l&15), nt=1 -> +1
  f16x8 Bf[KSZ][2][2];
  #pragma unroll
  for (int s = 0; s < KSZ; ++s)
    #pragma unroll
    for (int kh = 0; kh < 2; ++kh)
      #pragma unroll
      for (int nt = 0; nt < 2; ++nt) {
        int f  = 2 * (l & 15) + nt;
        int d0 = kh * 32 + (l >> 4) * 8;
        int byte = ((s * FILT + f) * DIM + d0) * 2;
        byte ^= (f & 7) << 4;
        Bf[s][kh][nt] = *reinterpret_cast<const f16x8*>(&ks[byte >> 1]);
      }

  float mx = -INFINITY, mn = INFINITY;
  int cur = 0;

  for (int it = 0; it < TPB; ++it) {
    // Counted vmcnt (r10-proven): newest 8 = S(it-1)[4] + L(it+1)[4]; in-order
    // retirement guarantees L(it) complete without waiting on fresh stores.
    if (it + 1 < TPB) {
      stage(cur ^ 1, it + 1);
      asm volatile("s_waitcnt vmcnt(8)" ::: "memory");
    } else {
      asm volatile("s_waitcnt vmcnt(4)" ::: "memory");   // newest 4 = S(T-2)
    }
    __builtin_amdgcn_sched_barrier(0);   // rule #18: pin ds_reads after the wait

    const float* xl = &xs[cur][0];
    f32x4 acc0 = (f32x4){0.f, 0.f, 0.f, 0.f};
    f32x4 acc1 = (f32x4){0.f, 0.f, 0.f, 0.f};

    #pragma unroll
    for (int s = 0; s < KSZ; ++s) {
      #pragma unroll
      for (int kh = 0; kh < 2; ++kh) {
        int ra = wv * RST + (l & 15) + s;   // rows 16,17 bleed: masked C-rows only
        int sg = kh * 8 + (l >> 4) * 2;
        int rb = ra & 7;
        f32x4 u0 = *reinterpret_cast<const f32x4*>(&xl[ra * DIM + ((sg    ) ^ rb) * 4]);
        f32x4 u1 = *reinterpret_cast<const f32x4*>(&xl[ra * DIM + ((sg + 1) ^ rb) * 4]);
        u32x4 pk;
        pk.x = __builtin_bit_cast(unsigned, __builtin_amdgcn_cvt_pkrtz(u0.x, u0.y));
        pk.y = __builtin_bit_cast(unsigned, __builtin_amdgcn_cvt_pkrtz(u0.z, u0.w));
        pk.z = __builtin_bit_cast(unsigned, __builtin_amdgcn_cvt_pkrtz(u1.x, u1.y));
        pk.w = __builtin_bit_cast(unsigned, __builtin_amdgcn_cvt_pkrtz(u1.z, u1.w));
        f16x8 av = __builtin_bit_cast(f16x8, pk);
        acc0 = __builtin_amdgcn_mfma_f32_16x16x32_f16(av, Bf[s][kh][0], acc0, 0, 0, 0);
        acc1 = __builtin_amdgcn_mfma_f32_16x16x32_f16(av, Bf[s][kh][1], acc1, 0, 0, 0);
      }
    }

    long gw0 = (long)(step0 + it) * WT + wv * RPW;
    #pragma unroll
    for (int r = 0; r < 4; ++r) {
      int wl = (l >> 4) * 4 + r;           // C-row = (lane>>4)*4+reg
      long gr = gw0 + wl;
      if (wl < RPW && gr < WOUT) {
        float v0 = acc0[r], v1 = acc1[r];  // filters 2*(l&15), 2*(l&15)+1
        mx = fmaxf(mx, fmaxf(v0, v1));
        mn = fminf(mn, fminf(v0, v1));
        float2 o; o.x = v0; o.y = v1;      // UNNORMALIZED; fixed up in phase 2
        *reinterpret_cast<float2*>(out + ((long)b * WOUT + gr) * FILT + 2 * (l & 15)) = o;
      }
    }
    cur ^= 1;
  }

  // ---- block min/max -> mm, then per-batch soft barrier (RELAXED polling)
  #pragma unroll
  for (int off = 32; off > 0; off >>= 1) {
    mx = fmaxf(mx, __shfl_down(mx, off));
    mn = fminf(mn, __shfl_down(mn, off));
  }
  if (l == 0) { red[wv * 2] = mx; red[wv * 2 + 1] = mn; }
  __syncthreads();
  if (t == 0) {
    float Mx = -INFINITY, Mn = INFINITY;
    #pragma unroll
    for (int w = 0; w < NW; ++w) {
      Mx = fmaxf(Mx, red[w * 2]);
      Mn = fminf(Mn, red[w * 2 + 1]);
    }
    __hip_atomic_store(&mm[(b * NBX + bx) * 2],     Mx,
                       __ATOMIC_RELEASE, __HIP_MEMORY_SCOPE_AGENT);
    __hip_atomic_store(&mm[(b * NBX + bx) * 2 + 1], Mn,
                       __ATOMIC_RELEASE, __HIP_MEMORY_SCOPE_AGENT);
    __hip_atomic_fetch_add(&cnt[b], 1u, __ATOMIC_ACQ_REL, __HIP_MEMORY_SCOPE_AGENT);
    // RELAXED spin: no per-iteration buffer_inv (that was the 1.73 TB/s cap)
    while (__hip_atomic_load(&cnt[b], __ATOMIC_RELAXED, __HIP_MEMORY_SCOPE_AGENT) < 4u)
      __builtin_amdgcn_s_sleep(8);
    // ONE acquire fence pairs with the arrivals' releases
    __builtin_amdgcn_fence(__ATOMIC_ACQUIRE, "agent");
    float GMx = -INFINITY, GMn = INFINITY;
    #pragma unroll
    for (int i = 0; i < NBX; ++i) {
      GMx = fmaxf(GMx, __hip_atomic_load(&mm[(b * NBX + i) * 2],
                                         __ATOMIC_RELAXED, __HIP_MEMORY_SCOPE_AGENT));
      GMn = fminf(GMn, __hip_atomic_load(&mm[(b * NBX + i) * 2 + 1],
                                         __ATOMIC_RELAXED, __HIP_MEMORY_SCOPE_AGENT));
    }
    red[0] = GMx; red[1] = GMn;
  }
  __syncthreads();

  // ---- phase 2: in-place normalize of own rows (dirty lines survived the
  // fence's invalidate -> own-L2 hits). Drain own stores first.
  asm volatile("s_waitcnt vmcnt(0)" ::: "memory");
  const float Mn = red[1];
  const float rs = 1.0f / (red[0] - Mn);

  for (int it = 0; it < TPB; ++it) {
    long gw0 = (long)(step0 + it) * WT + wv * RPW;
    #pragma unroll
    for (int r = 0; r < 4; ++r) {
      int wl = (l >> 4) * 4 + r;
      long gr = gw0 + wl;
      if (wl < RPW && gr < WOUT) {
        float2* p = reinterpret_cast<float2*>(out + ((long)b * WOUT + gr) * FILT + 2 * (l & 15));
        float2 v = *p;
        v.x = (v.x - Mn) * rs;
        v.y = (v.y - Mn) * rs;
        *p = v;
      }
    }
  }
}

extern "C" void kernel_launch(void* const* d_in, const int* in_sizes, int n_in,
                              void* d_out, int out_size, void* d_ws, size_t ws_size,
                              hipStream_t stream) {
  const float* x   = (const float*)d_in[0];
  const float* ker = (const float*)d_in[1];
  float* out = (float*)d_out;
  float*    mm  = (float*)d_ws;                      // 1024 floats (4 KB)
  unsigned* cnt = (unsigned*)((char*)d_ws + 4096);   // 128 arrival counters

  zero_cnt<<<dim3(1), dim3(128), 0, stream>>>(cnt);
  conv_norm<<<dim3(NBX * BATCH), dim3(512), 0, stream>>>(x, ker, out, mm, cnt);
}

// Round 18
// 115.234 us; speedup vs baseline: 2.0221x; 1.8020x over previous
//
#include <hip/hip_runtime.h>
#include <hip/hip_bf16.h>

#define BATCH  128
#define WIDTH  8192
#define DIM    64
#define FILT   32
#define KSZ    3
#define WOUT   8190
#define RPW    14     // output rows per wave per step
#define RST    16     // rows staged per wave per step
#define NW     8      // waves per block (512 threads)
#define WT     112    // NW*RPW output rows per block-step
#define TPB    19     // steps per block
#define NBX    4      // 4*19*112 = 8512 >= 8190
#define XR     (NW*RST + 2)   // 130 rows per buffer (2 pad rows: garbage, masked)

typedef __attribute__((ext_vector_type(8))) _Float16 f16x8;
typedef __attribute__((ext_vector_type(4))) float f32x4;
typedef __attribute__((ext_vector_type(4))) unsigned u32x4;

// Conv once (r10-proven): per-block min/max -> mm; conv values packed f16 ->
// c16. c16 viewed as u32 [b][w][16]: slot s holds filters {2s,2s+1} = flat
// f16 array [b][w][32].
__global__ __launch_bounds__(512, 4)
void conv_min(const float* __restrict__ x, const float* __restrict__ ker,
              unsigned* __restrict__ c16, float* __restrict__ mm)
{
  // Per-wave private double-buffered x rows: fp32; content swizzled:
  // xs[..][row][slot16] = x[row][slot16 ^ (row&7)].
  __shared__ __align__(16) float xs[2][XR * DIM];      // 66,560 B
  __shared__ __align__(16) short ks[KSZ * FILT * DIM]; // 12,288 B
  __shared__ float red[2 * NW];

  const int t  = threadIdx.x;
  const int l  = t & 63;
  const int wv = t >> 6;
  const int b  = blockIdx.y;
  const int step0 = blockIdx.x * TPB;
  const float* xb = x + (long)b * WIDTH * DIM;

  // Per-wave stage: 4 direct-to-LDS DMAs (1 KB = 4 rows) into OWN region.
  auto stage = [&](int bb, int step) {
    long gw0 = (long)(step0 + step) * WT + wv * RPW;
    char* lb = (char*)&xs[bb][0] + wv * (RST * DIM * 4);
    #pragma unroll
    for (int j = 0; j < 4; ++j) {
      int row_l = j * 4 + (l >> 4);
      int slot  = (l & 15) ^ (row_l & 7);
      long gr = gw0 + row_l;
      if (gr > WIDTH - 1) gr = WIDTH - 1;   // tail OOB guard (dup reads, L2-hot)
      __builtin_amdgcn_global_load_lds(
          (const __attribute__((address_space(1))) void*)(xb + gr * DIM + slot * 4),
          (__attribute__((address_space(3))) void*)(lb + j * 1024), 16, 0, 0);
    }
  };

  stage(0, 0);   // prologue prefetch; hides under weight staging

  // weights: fp32 [k][d][f] coalesced -> f16 LDS [k][f][d], XOR-swizzled (f&7)
  #pragma unroll
  for (int i = 0; i < 12; ++i) {
    int idx = t + i * 512;
    int k = idx >> 11, rem = idx & 2047;
    int d = rem >> 5,  f = rem & 31;
    _Float16 hv = (_Float16)ker[idx];
    int byte = ((k * FILT + f) * DIM + d) * 2;
    byte ^= (f & 7) << 4;
    ks[byte >> 1] = __builtin_bit_cast(short, hv);
  }
  __syncthreads();

  // Persistent B fragments: nt=0 -> filter 2*(l&15), nt=1 -> +1 (adjacent pair)
  f16x8 Bf[KSZ][2][2];
  #pragma unroll
  for (int s = 0; s < KSZ; ++s)
    #pragma unroll
    for (int kh = 0; kh < 2; ++kh)
      #pragma unroll
      for (int nt = 0; nt < 2; ++nt) {
        int f  = 2 * (l & 15) + nt;
        int d0 = kh * 32 + (l >> 4) * 8;
        int byte = ((s * FILT + f) * DIM + d0) * 2;
        byte ^= (f & 7) << 4;
        Bf[s][kh][nt] = *reinterpret_cast<const f16x8*>(&ks[byte >> 1]);
      }

  float mx = -INFINITY, mn = INFINITY;
  int cur = 0;

  for (int it = 0; it < TPB; ++it) {
    // Counted vmcnt: newest 8 = S(it-1)[4] + L(it+1)[4]; in-order retirement
    // guarantees L(it) complete without waiting on fresh stores.
    if (it + 1 < TPB) {
      stage(cur ^ 1, it + 1);
      asm volatile("s_waitcnt vmcnt(8)" ::: "memory");
    } else {
      asm volatile("s_waitcnt vmcnt(4)" ::: "memory");   // newest 4 = S(T-2)
    }
    __builtin_amdgcn_sched_barrier(0);   // rule #18: pin ds_reads after the wait

    const float* xl = &xs[cur][0];
    f32x4 acc0 = (f32x4){0.f, 0.f, 0.f, 0.f};
    f32x4 acc1 = (f32x4){0.f, 0.f, 0.f, 0.f};

    #pragma unroll
    for (int s = 0; s < KSZ; ++s) {
      #pragma unroll
      for (int kh = 0; kh < 2; ++kh) {
        int ra = wv * RST + (l & 15) + s;   // rows 16,17 bleed: masked C-rows only
        int sg = kh * 8 + (l >> 4) * 2;
        int rb = ra & 7;
        f32x4 u0 = *reinterpret_cast<const f32x4*>(&xl[ra * DIM + ((sg    ) ^ rb) * 4]);
        f32x4 u1 = *reinterpret_cast<const f32x4*>(&xl[ra * DIM + ((sg + 1) ^ rb) * 4]);
        u32x4 pk;
        pk.x = __builtin_bit_cast(unsigned, __builtin_amdgcn_cvt_pkrtz(u0.x, u0.y));
        pk.y = __builtin_bit_cast(unsigned, __builtin_amdgcn_cvt_pkrtz(u0.z, u0.w));
        pk.z = __builtin_bit_cast(unsigned, __builtin_amdgcn_cvt_pkrtz(u1.x, u1.y));
        pk.w = __builtin_bit_cast(unsigned, __builtin_amdgcn_cvt_pkrtz(u1.z, u1.w));
        f16x8 av = __builtin_bit_cast(f16x8, pk);
        acc0 = __builtin_amdgcn_mfma_f32_16x16x32_f16(av, Bf[s][kh][0], acc0, 0, 0, 0);
        acc1 = __builtin_amdgcn_mfma_f32_16x16x32_f16(av, Bf[s][kh][1], acc1, 0, 0, 0);
      }
    }

    long gw0 = (long)(step0 + it) * WT + wv * RPW;
    #pragma unroll
    for (int r = 0; r < 4; ++r) {
      int wl = (l >> 4) * 4 + r;           // C-row = (lane>>4)*4+reg
      long gr = gw0 + wl;
      if (wl < RPW && gr < WOUT) {
        float v0 = acc0[r], v1 = acc1[r];  // filters 2*(l&15), 2*(l&15)+1
        mx = fmaxf(mx, fmaxf(v0, v1));
        mn = fminf(mn, fminf(v0, v1));
        unsigned lo = __builtin_bit_cast(unsigned short, (_Float16)v0);
        unsigned hi = __builtin_bit_cast(unsigned short, (_Float16)v1);
        c16[((long)b * WOUT + gr) * 16 + (l & 15)] = lo | (hi << 16);
      }
    }
    cur ^= 1;
  }

  #pragma unroll
  for (int off = 32; off > 0; off >>= 1) {
    mx = fmaxf(mx, __shfl_down(mx, off));
    mn = fminf(mn, __shfl_down(mn, off));
  }
  if (l == 0) { red[wv * 2] = mx; red[wv * 2 + 1] = mn; }
  __syncthreads();
  if (t == 0) {
    float Mx = -INFINITY, Mn = INFINITY;
    #pragma unroll
    for (int w = 0; w < NW; ++w) {
      Mx = fmaxf(Mx, red[w * 2]);
      Mn = fminf(Mn, red[w * 2 + 1]);
    }
    mm[(b * NBX + blockIdx.x) * 2]     = Mx;
    mm[(b * NBX + blockIdx.x) * 2 + 1] = Mn;
  }
}

// Flat normalizer (r9-proven): c16 = flat f16 [b][w][32]; chunk c covers f16
// indices [c*8, c*8+8) -> 8 consecutive f32 outputs at the same flat position.
// Out stores are NONTEMPORAL: out is never re-read, so don't let 134 MB of
// output evict x from L2/L3 between graph replays.
__global__ __launch_bounds__(256)
void norm_out(const unsigned* __restrict__ c16, const float* __restrict__ mm,
              float* __restrict__ out)
{
  const int b = blockIdx.y;
  float mx = -INFINITY, mn = INFINITY;
  #pragma unroll
  for (int i = 0; i < NBX; ++i) {
    mx = fmaxf(mx, mm[(b * NBX + i) * 2]);
    mn = fminf(mn, mm[(b * NBX + i) * 2 + 1]);
  }
  const float rs = 1.0f / (mx - mn);

  const int c = blockIdx.x * 256 + threadIdx.x;   // u32x4 chunk within batch
  if (c < WOUT * 4) {                             // 8190*16/4 = 32760 chunks
    u32x4 v = *reinterpret_cast<const u32x4*>(c16 + ((long)b * WOUT) * 16 + (long)c * 4);
    long base = (long)b * (WOUT * FILT) + (long)c * 8;
    f32x4 o0, o1;
    #pragma unroll
    for (int j = 0; j < 2; ++j) {
      unsigned u = v[j];
      o0[2*j]   = ((float)__builtin_bit_cast(_Float16, (unsigned short)(u & 0xffffu)) - mn) * rs;
      o0[2*j+1] = ((float)__builtin_bit_cast(_Float16, (unsigned short)(u >> 16))      - mn) * rs;
    }
    #pragma unroll
    for (int j = 0; j < 2; ++j) {
      unsigned u = v[2+j];
      o1[2*j]   = ((float)__builtin_bit_cast(_Float16, (unsigned short)(u & 0xffffu)) - mn) * rs;
      o1[2*j+1] = ((float)__builtin_bit_cast(_Float16, (unsigned short)(u >> 16))      - mn) * rs;
    }
    __builtin_nontemporal_store(o0, reinterpret_cast<f32x4*>(out + base));
    __builtin_nontemporal_store(o1, reinterpret_cast<f32x4*>(out + base + 4));
  }
}

extern "C" void kernel_launch(void* const* d_in, const int* in_sizes, int n_in,
                              void* d_out, int out_size, void* d_ws, size_t ws_size,
                              hipStream_t stream) {
  const float* x   = (const float*)d_in[0];
  const float* ker = (const float*)d_in[1];
  float* out = (float*)d_out;
  float*    mm  = (float*)d_ws;                       // 1024 floats (4 KB)
  unsigned* c16 = (unsigned*)((char*)d_ws + 4096);    // 67 MB f16-pair intermediate

  conv_min<<<dim3(NBX, BATCH), dim3(512), 0, stream>>>(x, ker, c16, mm);
  norm_out<<<dim3(128, BATCH), dim3(256), 0, stream>>>(c16, mm, out);
}